// Round 20
// baseline (62.630 us; speedup 1.0000x reference)
//
#include <hip/hip_runtime.h>

typedef __bf16 bf16x8 __attribute__((ext_vector_type(8)));
typedef float  f32x4  __attribute__((ext_vector_type(4)));
typedef float  f32x16 __attribute__((ext_vector_type(16)));
typedef unsigned short ushort_t;

#define B_TOTAL 65536

// ---------------- helpers ----------------------------------------------------
__device__ __forceinline__ ushort_t f2bf(float f) {
  unsigned u = __builtin_bit_cast(unsigned, f);
  u += 0x7fffu + ((u >> 16) & 1u);          // RNE
  return (ushort_t)(u >> 16);
}
__device__ __forceinline__ unsigned pk2(float lo, float hi) {
  unsigned r;
  asm("v_cvt_pk_bf16_f32 %0, %1, %2" : "=v"(r) : "v"(lo), "v"(hi));
  return r;
}
__device__ __forceinline__ float lrelu(float v) { return v >= 0.f ? v : 0.1f * v; }
__device__ __forceinline__ bf16x8 ld_frag(const ushort_t* p8) {
  return __builtin_bit_cast(bf16x8, *(const uint4*)p8);
}
// LDS tiles in MFMA B-frag order: byte = tile*1024 + lane*16 (conflict-free)
__device__ __forceinline__ bf16x8 ld_tile(const ushort_t* base, int tile, int lane) {
  return __builtin_bit_cast(bf16x8,
      *(const uint4*)((const char*)base + tile * 1024 + lane * 16));
}
// frag-order address of scalar (col k, sample s15, subtile st) with 4 subtiles
__device__ __forceinline__ char* frag_addr4(ushort_t* base, int k, int s15, int st) {
  int kb = k >> 5, g = (k >> 3) & 3, i = k & 7;
  return (char*)base + (((kb * 4 + st) * 64) + s15 + g * 16) * 16 + i * 2;
}
__device__ __forceinline__ f32x4 mfma16(bf16x8 a, bf16x8 b, f32x4 c) {
  return __builtin_amdgcn_mfma_f32_16x16x32_bf16(a, b, c, 0, 0, 0);
}
__device__ __forceinline__ f32x16 mfma32(bf16x8 a, bf16x8 b, f32x16 c) {
  return __builtin_amdgcn_mfma_f32_32x32x16_bf16(a, b, c, 0, 0, 0);
}

// ---------------- Consolidated prep: packs + bn partial sums -----------------
struct PrepParams {
  const float* W1; const float* W2; const float* Wl;
  ushort_t* w1p; ushort_t* w2p; ushort_t* wlp;
  ushort_t* Apack; ushort_t* Bpack;
  const float* xc; float* ws;
  const float* wk[12];
};

__global__ __launch_bounds__(256) void prep_all(PrepParams q) {
  __shared__ float red[512];
  const int b = blockIdx.x, t = threadIdx.x;
  if (b < 688) {
    int u = b * 256 + t;
    if (u < 32768) {                                 // W1: K 48->64, N 512 (16x16 A-frag)
      int i = u & 7, lane = (u >> 3) & 63, kb = u >> 14;
      int k = kb * 32 + ((lane >> 4) << 3) + i;
      int n = (((u >> 9) & 31) << 4) + (lane & 15);
      q.w1p[u] = f2bf(k < 48 ? q.W1[k * 512 + n] : 0.f);
    } else if (u < 32768 + 131072) {                 // W2: 32x32x16 A-frag [kb32][nt8][64][8]
      int v = u - 32768;
      int i = v & 7, lane = (v >> 3) & 63;
      int rest = v >> 9;                             // kb*8 + nt
      int kb = rest >> 3, nt = rest & 7;
      int k = kb * 16 + ((lane >> 5) << 3) + i;
      int n = nt * 32 + (lane & 31);
      q.w2p[v] = f2bf(q.W2[k * 256 + n]);
    } else {                                         // Wlin: K 384, N 24->32 (16x16 A-frag)
      int v = u - (32768 + 131072);
      int i = v & 7, lane = (v >> 3) & 63, kb = v >> 10;
      int k = kb * 32 + ((lane >> 4) << 3) + i;
      int n = (((v >> 9) & 1) << 4) + (lane & 15);
      float val = 0.f;
      if (n < 24) {
        if (k < 108)       val = q.Wl[k * 24 + n];
        else if (k >= 128) val = q.Wl[(k - 20) * 24 + n];
      }
      q.wlp[v] = f2bf(val);
    }
  } else if (b < 792) {
    int u = (b - 688) * 256 + t;
    if (u < 20480) {
      int i = u & 7, lane = (u >> 3) & 63;
      int knt = u >> 9;
      int kb = knt / 5, nt = knt % 5;
      int k = kb * 32 + ((lane >> 4) << 3) + i;
      int n = nt * 16 + (lane & 15);
      float val = 0.f;
      if (n < 72 && k < 240) {
        int br = n / 12, ii = n - br * 12, ks = br + 1, lin = 240 - br;
        int si = ii * lin / 12, ei = ((ii + 1) * lin + 11) / 12;
        const float* wa = q.wk[2 * br];
        float acc = 0.f;
        for (int kk = 0; kk < ks; ++kk) {
          int j = k - kk;
          if (j >= si && j < ei) acc += wa[kk];
        }
        val = acc / (float)(ei - si);
      }
      q.Apack[u] = f2bf(val);
    } else {
      int v = u - 20480;
      int i = v & 7, lane = (v >> 3) & 63;
      int knt = v >> 9;
      int kb = knt / 3, nt = knt % 3;
      int kcol = kb * 32 + ((lane >> 4) << 3) + i;
      int n = nt * 16 + (lane & 15);
      float val = 0.f;
      if (n < 36 && kcol < 108) {
        int brk = kcol / 18, ii = kcol - brk * 18;
        int brn = n / 6, j = n - brn * 6;
        if (brk == brn && ii < 12) {
          int ks = brn + 1, lcb = 12 - 2 * brn;
          int sj = j * lcb / 6, ej = ((j + 1) * lcb + 5) / 6;
          const float* wb = q.wk[2 * brn + 1];
          float acc = 0.f;
          for (int kk = 0; kk < ks; ++kk) {
            int qq = ii - 2 * kk;
            if (qq >= sj && qq < ej) acc += wb[kk];
          }
          val = acc / (float)(ej - sj);
        }
      }
      q.Bpack[v] = f2bf(val);
    }
  } else {
    // bn partial sums (256 blocks x 256 samples)
    const int c = t & 15, g = t >> 4;
    const int r0 = (b - 792) * 256;
    float s = 0.f, qq = 0.f;
    for (int i = 0; i < 16; ++i) {
      float v = q.xc[(size_t)(r0 + g + i * 16) * 16 + c];
      s += v; qq += v * v;
    }
    red[t] = s; red[256 + t] = qq;
    __syncthreads();
    if (t < 16) {
      float ss = 0.f, sq = 0.f;
      for (int gg = 0; gg < 16; ++gg) { ss += red[gg * 16 + t]; sq += red[256 + gg * 16 + t]; }
      q.ws[(b - 792) * 32 + t] = ss;
      q.ws[(b - 792) * 32 + 16 + t] = sq;
    }
  }
}

__global__ __launch_bounds__(256) void bn_final(const float* __restrict__ ws_in,
                                                float* __restrict__ ws_out,
                                                const float* __restrict__ g_,
                                                const float* __restrict__ b_) {
  __shared__ float red[512];
  const int t = threadIdx.x;
  const int c = t & 15, g = t >> 4;
  float s = 0.f, q = 0.f;
  for (int i = 0; i < 16; ++i) {
    int blk = g * 16 + i;
    s += ws_in[blk * 32 + c];
    q += ws_in[blk * 32 + 16 + c];
  }
  red[t] = s; red[256 + t] = q;
  __syncthreads();
  if (t < 16) {
    float ss = 0.f, qq = 0.f;
    for (int gg = 0; gg < 16; ++gg) { ss += red[gg * 16 + t]; qq += red[256 + gg * 16 + t]; }
    float mean  = ss / (float)B_TOTAL;
    float var   = qq / (float)B_TOTAL - mean * mean;
    float scale = g_[t] / sqrtf(var + 1e-5f);
    ws_out[8192 + t]      = scale;
    ws_out[8192 + 16 + t] = b_[t] - mean * scale;
  }
}

// ---------------- Fully fused kernel: 64 samples / block, 16 waves -----------
// h1 quarter-pipelined; GEMM2 uses 32x32x16 MFMA (half LDS bytes per FLOP)
struct FusedParams {
  const float* xw;
  const int*   xcat;
  const float* xcont;
  const float* E0; const float* E1; const float* E2;
  const float* b1; const float* b2;
  const ushort_t* Apack; const ushort_t* Bpack;
  const ushort_t* w1p; const ushort_t* w2p; const ushort_t* wlp;
  const float* stats;
  float*       out;
};

__global__ __launch_bounds__(1024, 8) void fused_kernel(FusedParams p) {
  // LDS 56 KB -> 2 blocks/CU; 16 waves/block -> 32 waves/CU (HW ceiling).
  //   [0,32K)   s_xw frag[8kb][4st] (conv input) -> qbuf0[0,16K)+qbuf1[16K,32K)
  //             (h1 quarters in 32x32 B-frag order) -> s_h2 (16x16 B-frag, 32K)
  //   [32K,48K) s_cf  frag[4 kb][4 st]  (conv feats; persists to GEMM3)
  //   [48K,56K) s_x48 frag[2 kb][4 st]
  __shared__ __align__(16) char smem[57344];
  ushort_t* s_xw  = (ushort_t*)smem;
  ushort_t* s_h2  = (ushort_t*)smem;
  ushort_t* qbuf0 = (ushort_t*)smem;
  ushort_t* qbuf1 = (ushort_t*)(smem + 16384);
  ushort_t* s_cf  = (ushort_t*)(smem + 32768);
  ushort_t* s_x48 = (ushort_t*)(smem + 49152);

  const int t    = threadIdx.x;
  const int lane = t & 63;
  const int w    = t >> 6;          // 0..15
  const int quad = lane >> 4;
  const int s15  = lane & 15;
  const int s0   = blockIdx.x * 64;
  const f32x4 fzero = {0.f, 0.f, 0.f, 0.f};

  // ---- Stage: zero s_cf + pads, stage xw, build x48 (all frag-order)
  ((uint4*)s_cf)[t] = uint4{0, 0, 0, 0};       // 16 KB zero
  if (t < 128) {       // xw pad cols 240..255: kb7 -> tiles 28..31, bytes 512..1023
    *(uint4*)((char*)s_xw + (28 + (t >> 5)) * 1024 + 512 + (t & 31) * 16) = uint4{0, 0, 0, 0};
  } else if (t < 256) { // x48 pad cols 48..63: kb1 -> tiles 4..7
    int tt = t - 128;
    *(uint4*)((char*)s_x48 + (4 + (tt >> 5)) * 1024 + 512 + (tt & 31) * 16) = uint4{0, 0, 0, 0};
  }
  for (int u = t; u < 64 * 60; u += 1024) {    // xw cols 4*m4..4*m4+3 -> frag uint2
    int s = u / 60, m4 = u - s * 60;
    float4 v = *(const float4*)(p.xw + (size_t)(s0 + s) * 240 + 4 * m4);
    uint2 pkv; pkv.x = pk2(v.x, v.y); pkv.y = pk2(v.z, v.w);
    int tile = (m4 >> 3) * 4 + (s >> 4);
    *(uint2*)((char*)s_xw + (tile * 64 + (s & 15) + ((m4 >> 1) & 3) * 16) * 16
              + (m4 & 1) * 8) = pkv;
  }
  for (int u = t; u < 64 * 48; u += 1024) {    // x48 gather (bn via p.stats)
    int s = u / 48, c = u - s * 48, gs = s0 + s;
    float v;
    if (c < 20)      v = p.E0[(size_t)p.xcat[gs * 3 + 0] * 20 + c];
    else if (c < 24) v = p.E1[(size_t)p.xcat[gs * 3 + 1] * 4 + (c - 20)];
    else if (c < 32) v = p.E2[(size_t)p.xcat[gs * 3 + 2] * 8 + (c - 24)];
    else { int cc = c - 32; v = p.xcont[(size_t)gs * 16 + cc] * p.stats[cc] + p.stats[16 + cc]; }
    *(ushort_t*)frag_addr4(s_x48, c, s & 15, s >> 4) = f2bf(v);
  }
  __syncthreads();   // ---- A

  // ---- P1: GEMM0a  FA[72 n][64 samp] = leaky(xw @ A) -> s_cf col n+6*br
  auto do0a = [&](int nt, int st) {
    f32x4 acc = fzero;
    #pragma unroll
    for (int kb = 0; kb < 8; ++kb) {
      bf16x8 a = ld_frag(p.Apack + (size_t)((kb * 5 + nt) * 64 + lane) * 8);
      bf16x8 b = ld_tile(s_xw, kb * 4 + st, lane);
      acc = mfma16(a, b, acc);
    }
    int n0 = nt * 16 + quad * 4;
    int br = n0 / 12;                 // pad n>=72 -> cols 108..115 (writes zeros)
    int col0 = n0 + 6 * br;
    *(unsigned*)frag_addr4(s_cf, col0, s15, st)     = pk2(lrelu(acc[0]), lrelu(acc[1]));
    *(unsigned*)frag_addr4(s_cf, col0 + 2, s15, st) = pk2(lrelu(acc[2]), lrelu(acc[3]));
  };
  do0a(w % 5, w / 5);                 // 20 tiles over 16 waves
  if (w < 4) do0a((w + 16) % 5, (w + 16) / 5);

  const int nt2 = w >> 1;             // GEMM2: n-tile of 32 (0..7)
  const int st2 = w & 1;              //        sample-tile of 32 (0..1)
  uint4 pa[2];                         // W2 ring, depth 2 (32x32 A-frags)
  pa[0] = *(const uint4*)(p.w2p + (size_t)((0 * 8 + nt2) * 64 + lane) * 8);
  pa[1] = *(const uint4*)(p.w2p + (size_t)((1 * 8 + nt2) * 64 + lane) * 8);
  __syncthreads();   // ---- B

  // ---- GEMM1 quarter: h1 features [q*128, q*128+128) -> qbuf (32x32 B-frag)
  auto gemm1_q = [&](int q, ushort_t* qbuf) {
    int ntl = w & 7;                   // local feature 16-block = kb16-local
    int gnt = q * 8 + ntl;
    bf16x8 a0 = ld_frag(p.w1p + (size_t)((0 * 32 + gnt) * 64 + lane) * 8);
    bf16x8 a1 = ld_frag(p.w1p + (size_t)((32 + gnt) * 64 + lane) * 8);
    int n0l = ntl * 16 + quad * 4;
    float4 bb = *(const float4*)(p.b1 + q * 128 + n0l);
    int sh2 = (w >> 3) * 2;            // st pair {0,1} or {2,3}
    #pragma unroll
    for (int sj = 0; sj < 2; ++sj) {
      int st = sh2 + sj;
      bf16x8 b0 = ld_tile(s_x48, st, lane);
      bf16x8 b1 = ld_tile(s_x48, 4 + st, lane);
      f32x4 acc = mfma16(a0, b0, fzero);
      acc = mfma16(a1, b1, acc);
      float v0 = fmaxf(acc[0] + bb.x, 0.f);
      float v1 = fmaxf(acc[1] + bb.y, 0.f);
      float v2 = fmaxf(acc[2] + bb.z, 0.f);
      float v3 = fmaxf(acc[3] + bb.w, 0.f);
      uint2 pkv; pkv.x = pk2(v0, v1); pkv.y = pk2(v2, v3);
      // 32x32 B-frag write: k=feature (4 consecutive), col=sample
      int s = st * 16 + s15;
      int tile = ntl * 2 + (s >> 5);
      int lanep = ((quad >> 1) << 5) | (s & 31);
      *(uint2*)((char*)qbuf + (tile * 64 + lanep) * 16 + (quad & 1) * 8) = pkv;
    }
  };

  f32x16 acc2;
  #pragma unroll
  for (int ii = 0; ii < 16; ++ii) acc2[ii] = 0.f;

  // ---- GEMM2 quarter: 8 K16-blocks from qbuf; one 32x32x16 MFMA each
  auto gemm2_q = [&](int q, const ushort_t* qbuf) {
    #pragma unroll
    for (int kk = 0; kk < 8; ++kk) {
      int kb = q * 8 + kk;
      bf16x8 a0 = __builtin_bit_cast(bf16x8, pa[kb & 1]);
      if (kb + 2 < 32)
        pa[kb & 1] = *(const uint4*)(p.w2p + (size_t)(((kb + 2) * 8 + nt2) * 64 + lane) * 8);
      bf16x8 b = ld_tile(qbuf, kk * 2 + st2, lane);
      acc2 = mfma32(a0, b, acc2);
    }
  };

  // ---- P2: GEMM0b accumulate + G1(q0 -> buf0)
  const int ntB = w % 3, stB = w / 3;     // GEMM0b: 12 tiles, waves 0..11
  f32x4 accB = fzero;
  if (w < 12) {
    #pragma unroll
    for (int kb = 0; kb < 4; ++kb) {
      bf16x8 a = ld_frag(p.Bpack + (size_t)((kb * 3 + ntB) * 64 + lane) * 8);
      bf16x8 b = ld_tile(s_cf, kb * 4 + stB, lane);
      accB = mfma16(a, b, accB);
    }
  }
  gemm1_q(0, qbuf0);
  __syncthreads();   // ---- C

  // ---- P3: fb writes + G2(q0) + G1(q1 -> buf1)
  if (w < 12) {   // fb: n=br*6+j -> col n+12*(br+1)
    int n0 = ntB * 16 + quad * 4;
    if (n0 < 36) {
      int br0 = n0 / 6, c0 = n0 + 12 * (br0 + 1);
      int n2 = n0 + 2, br2 = n2 / 6, c2 = n2 + 12 * (br2 + 1);
      *(unsigned*)frag_addr4(s_cf, c0, s15, stB) = pk2(lrelu(accB[0]), lrelu(accB[1]));
      *(unsigned*)frag_addr4(s_cf, c2, s15, stB) = pk2(lrelu(accB[2]), lrelu(accB[3]));
    }
  }
  gemm2_q(0, qbuf0);
  gemm1_q(1, qbuf1);
  __syncthreads();   // ---- D

  // ---- P4: G2(q1) + G1(q2 -> buf0)
  gemm2_q(1, qbuf1);
  gemm1_q(2, qbuf0);
  __syncthreads();   // ---- E

  // ---- P5: G2(q2) + G1(q3 -> buf1)
  gemm2_q(2, qbuf0);
  gemm1_q(3, qbuf1);
  __syncthreads();   // ---- F

  // ---- P6: G2(q3)
  gemm2_q(3, qbuf1);
  __syncthreads();   // ---- G

  // ---- P7: h2 epilogue: 32x32 C/D (col=lane&31, row=(r&3)+8*(r>>2)+4*(lane>>5))
  //      -> s_h2 in GEMM3's 16x16 B-frag format (Wlin-K 128..383)
  {
    int s  = st2 * 32 + (lane & 31);
    #pragma unroll
    for (int rq = 0; rq < 4; ++rq) {
      int nb = 8 * rq + 4 * (lane >> 5);        // n_local base (0 mod 4)
      int ng = nt2 * 32 + nb;                   // global n (0..255)
      float4 bb = *(const float4*)(p.b2 + ng);
      float v0 = fmaxf(acc2[4 * rq + 0] + bb.x, 0.f);
      float v1 = fmaxf(acc2[4 * rq + 1] + bb.y, 0.f);
      float v2 = fmaxf(acc2[4 * rq + 2] + bb.z, 0.f);
      float v3 = fmaxf(acc2[4 * rq + 3] + bb.w, 0.f);
      uint2 pkv; pkv.x = pk2(v0, v1); pkv.y = pk2(v2, v3);
      int tile  = nt2 * 4 + (s >> 4);           // (ng>>5)*4 + (s>>4)
      int lanep = (s & 15) + (((ng >> 3) & 3) << 4);
      *(uint2*)((char*)s_h2 + (tile * 64 + lanep) * 16 + (ng & 7) * 2) = pkv;
    }
  }
  __syncthreads();   // ---- H

  // ---- P8: GEMM3  out[64][24] = [cf(K0..127) | h2(K128..383)] @ Wlin
  if (w < 8) {
    const int st = w & 3, nt = w >> 2;
    f32x4 acc = fzero;
    #pragma unroll
    for (int kb = 0; kb < 12; ++kb) {
      bf16x8 a = ld_frag(p.wlp + (size_t)((kb * 2 + nt) * 64 + lane) * 8);
      bf16x8 b = (kb < 4) ? ld_tile(s_cf, kb * 4 + st, lane)
                          : ld_tile(s_h2, (kb - 4) * 4 + st, lane);
      acc = mfma16(a, b, acc);
    }
    int n0 = nt * 16 + quad * 4;
    if (n0 < 24) {
      int sg = s0 + st * 16 + s15;
      *(float2*)(p.out + (size_t)sg * 24 + n0)     = make_float2(acc[0], acc[1]);
      *(float2*)(p.out + (size_t)sg * 24 + n0 + 2) = make_float2(acc[2], acc[3]);
    }
  }
}

// ---------------- launch -----------------------------------------------------
extern "C" void kernel_launch(void* const* d_in, const int* in_sizes, int n_in,
                              void* d_out, int out_size, void* d_ws, size_t ws_size,
                              hipStream_t stream) {
  const float* xcont = (const float*)d_in[2];
  float* ws  = (float*)d_ws;
  char*  wsb = (char*)d_ws;
  ushort_t* w1p   = (ushort_t*)(wsb + 36864);    //  64 KB
  ushort_t* w2p   = (ushort_t*)(wsb + 102400);   // 256 KB
  ushort_t* wlp   = (ushort_t*)(wsb + 364544);   //  24 KB
  ushort_t* Apack = (ushort_t*)(wsb + 389120);   //  40 KB
  ushort_t* Bpack = (ushort_t*)(wsb + 430080);   //  12 KB

  PrepParams q;
  q.W1 = (const float*)d_in[20]; q.W2 = (const float*)d_in[22]; q.Wl = (const float*)d_in[24];
  q.w1p = w1p; q.w2p = w2p; q.wlp = wlp;
  q.Apack = Apack; q.Bpack = Bpack;
  q.xc = xcont; q.ws = ws;
  for (int i = 0; i < 12; ++i) q.wk[i] = (const float*)d_in[3 + i];
  prep_all<<<1048, 256, 0, stream>>>(q);
  bn_final<<<1, 256, 0, stream>>>(ws, ws, (const float*)d_in[18], (const float*)d_in[19]);

  FusedParams p;
  p.xw    = (const float*)d_in[0];
  p.xcat  = (const int*)d_in[1];
  p.xcont = xcont;
  p.E0 = (const float*)d_in[15]; p.E1 = (const float*)d_in[16]; p.E2 = (const float*)d_in[17];
  p.b1 = (const float*)d_in[21]; p.b2 = (const float*)d_in[23];
  p.Apack = Apack; p.Bpack = Bpack;
  p.w1p = w1p; p.w2p = w2p; p.wlp = wlp;
  p.stats = ws + 8192;
  p.out = (float*)d_out;
  fused_kernel<<<B_TOTAL / 64, 1024, 0, stream>>>(p);
}

// Round 21
// 56.376 us; speedup vs baseline: 1.1109x; 1.1109x over previous
//
#include <hip/hip_runtime.h>

typedef __bf16 bf16x8 __attribute__((ext_vector_type(8)));
typedef float  f32x4  __attribute__((ext_vector_type(4)));
typedef unsigned short ushort_t;

#define B_TOTAL 65536

// ---------------- helpers ----------------------------------------------------
__device__ __forceinline__ ushort_t f2bf(float f) {
  unsigned u = __builtin_bit_cast(unsigned, f);
  u += 0x7fffu + ((u >> 16) & 1u);          // RNE
  return (ushort_t)(u >> 16);
}
__device__ __forceinline__ unsigned pk2(float lo, float hi) {
  unsigned r;
  asm("v_cvt_pk_bf16_f32 %0, %1, %2" : "=v"(r) : "v"(lo), "v"(hi));
  return r;
}
__device__ __forceinline__ float lrelu(float v) { return v >= 0.f ? v : 0.1f * v; }
__device__ __forceinline__ bf16x8 ld_frag(const ushort_t* p8) {
  return __builtin_bit_cast(bf16x8, *(const uint4*)p8);
}
// LDS tiles in MFMA B-frag order: byte = tile*1024 + lane*16 (conflict-free)
__device__ __forceinline__ bf16x8 ld_tile(const ushort_t* base, int tile, int lane) {
  return __builtin_bit_cast(bf16x8,
      *(const uint4*)((const char*)base + tile * 1024 + lane * 16));
}
// frag-order address of scalar (col k, sample s15, subtile st) with 4 subtiles
__device__ __forceinline__ char* frag_addr4(ushort_t* base, int k, int s15, int st) {
  int kb = k >> 5, g = (k >> 3) & 3, i = k & 7;
  return (char*)base + (((kb * 4 + st) * 64) + s15 + g * 16) * 16 + i * 2;
}
__device__ __forceinline__ f32x4 mfma16(bf16x8 a, bf16x8 b, f32x4 c) {
  return __builtin_amdgcn_mfma_f32_16x16x32_bf16(a, b, c, 0, 0, 0);
}

// ---------------- Consolidated prep: packs + bn partial sums -----------------
struct PrepParams {
  const float* W1; const float* W2; const float* Wl;
  ushort_t* w1p; ushort_t* w2p; ushort_t* wlp;
  ushort_t* Apack; ushort_t* Bpack;
  const float* xc; float* ws;
  const float* wk[12];
};

__global__ __launch_bounds__(256) void prep_all(PrepParams q) {
  __shared__ float red[512];
  const int b = blockIdx.x, t = threadIdx.x;
  if (b < 688) {
    int u = b * 256 + t;
    if (u < 32768) {                                 // W1: K 48->64, N 512
      int i = u & 7, lane = (u >> 3) & 63, kb = u >> 14;
      int k = kb * 32 + ((lane >> 4) << 3) + i;
      int n = (((u >> 9) & 31) << 4) + (lane & 15);
      q.w1p[u] = f2bf(k < 48 ? q.W1[k * 512 + n] : 0.f);
    } else if (u < 32768 + 131072) {                 // W2: K 512, N 256
      int v = u - 32768;
      int i = v & 7, lane = (v >> 3) & 63, kb = v >> 13;
      int k = kb * 32 + ((lane >> 4) << 3) + i;
      int n = (((v >> 9) & 15) << 4) + (lane & 15);
      q.w2p[v] = f2bf(q.W2[k * 256 + n]);
    } else {                                         // Wlin: K 384, N 24->32
      int v = u - (32768 + 131072);
      int i = v & 7, lane = (v >> 3) & 63, kb = v >> 10;
      int k = kb * 32 + ((lane >> 4) << 3) + i;
      int n = (((v >> 9) & 1) << 4) + (lane & 15);
      float val = 0.f;
      if (n < 24) {
        if (k < 108)       val = q.Wl[k * 24 + n];
        else if (k >= 128) val = q.Wl[(k - 20) * 24 + n];
      }
      q.wlp[v] = f2bf(val);
    }
  } else if (b < 792) {
    int u = (b - 688) * 256 + t;
    if (u < 20480) {
      int i = u & 7, lane = (u >> 3) & 63;
      int knt = u >> 9;
      int kb = knt / 5, nt = knt % 5;
      int k = kb * 32 + ((lane >> 4) << 3) + i;
      int n = nt * 16 + (lane & 15);
      float val = 0.f;
      if (n < 72 && k < 240) {
        int br = n / 12, ii = n - br * 12, ks = br + 1, lin = 240 - br;
        int si = ii * lin / 12, ei = ((ii + 1) * lin + 11) / 12;
        const float* wa = q.wk[2 * br];
        float acc = 0.f;
        for (int kk = 0; kk < ks; ++kk) {
          int j = k - kk;
          if (j >= si && j < ei) acc += wa[kk];
        }
        val = acc / (float)(ei - si);
      }
      q.Apack[u] = f2bf(val);
    } else {
      int v = u - 20480;
      int i = v & 7, lane = (v >> 3) & 63;
      int knt = v >> 9;
      int kb = knt / 3, nt = knt % 3;
      int kcol = kb * 32 + ((lane >> 4) << 3) + i;
      int n = nt * 16 + (lane & 15);
      float val = 0.f;
      if (n < 36 && kcol < 108) {
        int brk = kcol / 18, ii = kcol - brk * 18;
        int brn = n / 6, j = n - brn * 6;
        if (brk == brn && ii < 12) {
          int ks = brn + 1, lcb = 12 - 2 * brn;
          int sj = j * lcb / 6, ej = ((j + 1) * lcb + 5) / 6;
          const float* wb = q.wk[2 * brn + 1];
          float acc = 0.f;
          for (int kk = 0; kk < ks; ++kk) {
            int qq = ii - 2 * kk;
            if (qq >= sj && qq < ej) acc += wb[kk];
          }
          val = acc / (float)(ej - sj);
        }
      }
      q.Bpack[v] = f2bf(val);
    }
  } else {
    // bn partial sums (256 blocks x 256 samples)
    const int c = t & 15, g = t >> 4;
    const int r0 = (b - 792) * 256;
    float s = 0.f, qq = 0.f;
    for (int i = 0; i < 16; ++i) {
      float v = q.xc[(size_t)(r0 + g + i * 16) * 16 + c];
      s += v; qq += v * v;
    }
    red[t] = s; red[256 + t] = qq;
    __syncthreads();
    if (t < 16) {
      float ss = 0.f, sq = 0.f;
      for (int gg = 0; gg < 16; ++gg) { ss += red[gg * 16 + t]; sq += red[256 + gg * 16 + t]; }
      q.ws[(b - 792) * 32 + t] = ss;
      q.ws[(b - 792) * 32 + 16 + t] = sq;
    }
  }
}

__global__ __launch_bounds__(256) void bn_final(const float* __restrict__ ws_in,
                                                float* __restrict__ ws_out,
                                                const float* __restrict__ g_,
                                                const float* __restrict__ b_) {
  __shared__ float red[512];
  const int t = threadIdx.x;
  const int c = t & 15, g = t >> 4;
  float s = 0.f, q = 0.f;
  for (int i = 0; i < 16; ++i) {
    int blk = g * 16 + i;
    s += ws_in[blk * 32 + c];
    q += ws_in[blk * 32 + 16 + c];
  }
  red[t] = s; red[256 + t] = q;
  __syncthreads();
  if (t < 16) {
    float ss = 0.f, qq = 0.f;
    for (int gg = 0; gg < 16; ++gg) { ss += red[gg * 16 + t]; qq += red[256 + gg * 16 + t]; }
    float mean  = ss / (float)B_TOTAL;
    float var   = qq / (float)B_TOTAL - mean * mean;
    float scale = g_[t] / sqrtf(var + 1e-5f);
    ws_out[8192 + t]      = scale;
    ws_out[8192 + 16 + t] = b_[t] - mean * scale;
  }
}

// ---------------- Fully fused kernel: 64 samples / block, 16 waves -----------
// h1 quarter-pipelined: G2(q) overlaps G1(q+1) in double-buffered 16KB quarters
struct FusedParams {
  const float* xw;
  const int*   xcat;
  const float* xcont;
  const float* E0; const float* E1; const float* E2;
  const float* b1; const float* b2;
  const ushort_t* Apack; const ushort_t* Bpack;
  const ushort_t* w1p; const ushort_t* w2p; const ushort_t* wlp;
  const float* stats;
  float*       out;
};

__global__ __launch_bounds__(1024, 8) void fused_kernel(FusedParams p) {
  // LDS 56 KB -> 2 blocks/CU; 16 waves/block -> 32 waves/CU (HW ceiling).
  //   [0,32K)   s_xw frag[8kb][4st] (conv input) -> qbuf0[0,16K)+qbuf1[16K,32K)
  //             (h1 quarters, dbuf) -> s_h2 frag[8kb][4st] (GEMM2 out, 32K)
  //   [32K,48K) s_cf  frag[4 kb][4 st]  (conv feats; persists to GEMM3)
  //   [48K,56K) s_x48 frag[2 kb][4 st]
  __shared__ __align__(16) char smem[57344];
  ushort_t* s_xw  = (ushort_t*)smem;
  ushort_t* s_h2  = (ushort_t*)smem;
  ushort_t* qbuf0 = (ushort_t*)smem;
  ushort_t* qbuf1 = (ushort_t*)(smem + 16384);
  ushort_t* s_cf  = (ushort_t*)(smem + 32768);
  ushort_t* s_x48 = (ushort_t*)(smem + 49152);

  const int t    = threadIdx.x;
  const int lane = t & 63;
  const int w    = t >> 6;          // 0..15
  const int quad = lane >> 4;
  const int s15  = lane & 15;
  const int s0   = blockIdx.x * 64;
  const f32x4 fzero = {0.f, 0.f, 0.f, 0.f};

  // ---- Stage: zero s_cf + pads, stage xw, build x48 (all frag-order)
  ((uint4*)s_cf)[t] = uint4{0, 0, 0, 0};       // 16 KB zero
  if (t < 128) {       // xw pad cols 240..255: kb7 -> tiles 28..31, bytes 512..1023
    *(uint4*)((char*)s_xw + (28 + (t >> 5)) * 1024 + 512 + (t & 31) * 16) = uint4{0, 0, 0, 0};
  } else if (t < 256) { // x48 pad cols 48..63: kb1 -> tiles 4..7
    int tt = t - 128;
    *(uint4*)((char*)s_x48 + (4 + (tt >> 5)) * 1024 + 512 + (tt & 31) * 16) = uint4{0, 0, 0, 0};
  }
  for (int u = t; u < 64 * 60; u += 1024) {    // xw cols 4*m4..4*m4+3 -> frag uint2
    int s = u / 60, m4 = u - s * 60;
    float4 v = *(const float4*)(p.xw + (size_t)(s0 + s) * 240 + 4 * m4);
    uint2 pkv; pkv.x = pk2(v.x, v.y); pkv.y = pk2(v.z, v.w);
    int tile = (m4 >> 3) * 4 + (s >> 4);
    *(uint2*)((char*)s_xw + (tile * 64 + (s & 15) + ((m4 >> 1) & 3) * 16) * 16
              + (m4 & 1) * 8) = pkv;
  }
  for (int u = t; u < 64 * 48; u += 1024) {    // x48 gather (bn via p.stats)
    int s = u / 48, c = u - s * 48, gs = s0 + s;
    float v;
    if (c < 20)      v = p.E0[(size_t)p.xcat[gs * 3 + 0] * 20 + c];
    else if (c < 24) v = p.E1[(size_t)p.xcat[gs * 3 + 1] * 4 + (c - 20)];
    else if (c < 32) v = p.E2[(size_t)p.xcat[gs * 3 + 2] * 8 + (c - 24)];
    else { int cc = c - 32; v = p.xcont[(size_t)gs * 16 + cc] * p.stats[cc] + p.stats[16 + cc]; }
    *(ushort_t*)frag_addr4(s_x48, c, s & 15, s >> 4) = f2bf(v);
  }
  __syncthreads();   // ---- A

  // ---- P1: GEMM0a  FA[72 n][64 samp] = leaky(xw @ A) -> s_cf col n+6*br
  auto do0a = [&](int nt, int st) {
    f32x4 acc = fzero;
    #pragma unroll
    for (int kb = 0; kb < 8; ++kb) {
      bf16x8 a = ld_frag(p.Apack + (size_t)((kb * 5 + nt) * 64 + lane) * 8);
      bf16x8 b = ld_tile(s_xw, kb * 4 + st, lane);
      acc = mfma16(a, b, acc);
    }
    int n0 = nt * 16 + quad * 4;
    int br = n0 / 12;                 // pad n>=72 -> cols 108..115 (writes zeros)
    int col0 = n0 + 6 * br;
    *(unsigned*)frag_addr4(s_cf, col0, s15, st)     = pk2(lrelu(acc[0]), lrelu(acc[1]));
    *(unsigned*)frag_addr4(s_cf, col0 + 2, s15, st) = pk2(lrelu(acc[2]), lrelu(acc[3]));
  };
  do0a(w % 5, w / 5);                 // 20 tiles over 16 waves
  if (w < 4) do0a((w + 16) % 5, (w + 16) / 5);

  uint4 pa[2];                         // W2 ring (wave w owns n-tile w)
  pa[0] = *(const uint4*)(p.w2p + (size_t)((0 * 16 + w) * 64 + lane) * 8);
  pa[1] = *(const uint4*)(p.w2p + (size_t)((1 * 16 + w) * 64 + lane) * 8);
  __syncthreads();   // ---- B

  // ---- GEMM1 quarter: h1 n-range [q*128, q*128+128) -> qbuf
  auto gemm1_q = [&](int q, ushort_t* qbuf) {
    int ntl = w & 7;                   // local n-tile 0..7
    int gnt = q * 8 + ntl;
    bf16x8 a0 = ld_frag(p.w1p + (size_t)((0 * 32 + gnt) * 64 + lane) * 8);
    bf16x8 a1 = ld_frag(p.w1p + (size_t)((32 + gnt) * 64 + lane) * 8);
    int n0l = ntl * 16 + quad * 4;
    float4 bb = *(const float4*)(p.b1 + q * 128 + n0l);
    int kbl = ntl >> 1;
    int g   = (ntl * 2 + (quad >> 1)) & 3;
    int sh2 = (w >> 3) * 2;            // st pair {0,1} or {2,3}
    #pragma unroll
    for (int sj = 0; sj < 2; ++sj) {
      int st = sh2 + sj;
      bf16x8 b0 = ld_tile(s_x48, st, lane);
      bf16x8 b1 = ld_tile(s_x48, 4 + st, lane);
      f32x4 acc = mfma16(a0, b0, fzero);
      acc = mfma16(a1, b1, acc);
      float v0 = fmaxf(acc[0] + bb.x, 0.f);
      float v1 = fmaxf(acc[1] + bb.y, 0.f);
      float v2 = fmaxf(acc[2] + bb.z, 0.f);
      float v3 = fmaxf(acc[3] + bb.w, 0.f);
      uint2 pkv; pkv.x = pk2(v0, v1); pkv.y = pk2(v2, v3);
      *(uint2*)((char*)qbuf + ((kbl * 4 + st) * 64 + s15 + g * 16) * 16
                + (quad & 1) * 8) = pkv;
    }
  };

  f32x4 acc2[4];
  #pragma unroll
  for (int st = 0; st < 4; ++st) acc2[st] = fzero;

  // ---- GEMM2 quarter: kb = q*4..q*4+3 from qbuf; wave w owns n-tile w
  auto gemm2_q = [&](int q, const ushort_t* qbuf) {
    #pragma unroll
    for (int kk = 0; kk < 4; ++kk) {
      int kb = q * 4 + kk;
      bf16x8 a0 = __builtin_bit_cast(bf16x8, pa[kb & 1]);
      if (kb + 2 < 16)
        pa[kb & 1] = *(const uint4*)(p.w2p + (size_t)(((kb + 2) * 16 + w) * 64 + lane) * 8);
      #pragma unroll
      for (int st = 0; st < 4; ++st) {
        bf16x8 b = ld_tile(qbuf, kk * 4 + st, lane);
        acc2[st] = mfma16(a0, b, acc2[st]);
      }
    }
  };

  // ---- P2: GEMM0b accumulate + G1(q0 -> buf0)
  const int ntB = w % 3, stB = w / 3;     // GEMM0b: 12 tiles, waves 0..11
  f32x4 accB = fzero;
  if (w < 12) {
    #pragma unroll
    for (int kb = 0; kb < 4; ++kb) {
      bf16x8 a = ld_frag(p.Bpack + (size_t)((kb * 3 + ntB) * 64 + lane) * 8);
      bf16x8 b = ld_tile(s_cf, kb * 4 + stB, lane);
      accB = mfma16(a, b, accB);
    }
  }
  gemm1_q(0, qbuf0);
  __syncthreads();   // ---- C

  // ---- P3: fb writes + G2(q0) + G1(q1 -> buf1)
  if (w < 12) {   // fb: n=br*6+j -> col n+12*(br+1)
    int n0 = ntB * 16 + quad * 4;
    if (n0 < 36) {
      int br0 = n0 / 6, c0 = n0 + 12 * (br0 + 1);
      int n2 = n0 + 2, br2 = n2 / 6, c2 = n2 + 12 * (br2 + 1);
      *(unsigned*)frag_addr4(s_cf, c0, s15, stB) = pk2(lrelu(accB[0]), lrelu(accB[1]));
      *(unsigned*)frag_addr4(s_cf, c2, s15, stB) = pk2(lrelu(accB[2]), lrelu(accB[3]));
    }
  }
  gemm2_q(0, qbuf0);
  gemm1_q(1, qbuf1);
  __syncthreads();   // ---- D

  // ---- P4: G2(q1) + G1(q2 -> buf0)
  gemm2_q(1, qbuf1);
  gemm1_q(2, qbuf0);
  __syncthreads();   // ---- E

  // ---- P5: G2(q2) + G1(q3 -> buf1)
  gemm2_q(2, qbuf0);
  gemm1_q(3, qbuf1);
  __syncthreads();   // ---- F

  // ---- P6: G2(q3)
  gemm2_q(3, qbuf1);
  __syncthreads();   // ---- G

  // ---- P7: h2 epilogue -> s_h2 frag storage (Wlin-K 128..383), full 32K region
  {
    int n0 = w * 16 + quad * 4;
    float4 bb = *(const float4*)(p.b2 + n0);
    int kbh = w >> 1;
    int g   = (w * 2 + (quad >> 1)) & 3;
    #pragma unroll
    for (int st = 0; st < 4; ++st) {
      float v0 = fmaxf(acc2[st][0] + bb.x, 0.f);
      float v1 = fmaxf(acc2[st][1] + bb.y, 0.f);
      float v2 = fmaxf(acc2[st][2] + bb.z, 0.f);
      float v3 = fmaxf(acc2[st][3] + bb.w, 0.f);
      uint2 pkv; pkv.x = pk2(v0, v1); pkv.y = pk2(v2, v3);
      *(uint2*)((char*)s_h2 + ((kbh * 4 + st) * 64 + s15 + g * 16) * 16
                + (quad & 1) * 8) = pkv;
    }
  }
  __syncthreads();   // ---- H

  // ---- P8: GEMM3  out[64][24] = [cf(K0..127) | h2(K128..383)] @ Wlin
  if (w < 8) {
    const int st = w & 3, nt = w >> 2;
    f32x4 acc = fzero;
    #pragma unroll
    for (int kb = 0; kb < 12; ++kb) {
      bf16x8 a = ld_frag(p.wlp + (size_t)((kb * 2 + nt) * 64 + lane) * 8);
      bf16x8 b = (kb < 4) ? ld_tile(s_cf, kb * 4 + st, lane)
                          : ld_tile(s_h2, (kb - 4) * 4 + st, lane);
      acc = mfma16(a, b, acc);
    }
    int n0 = nt * 16 + quad * 4;
    if (n0 < 24) {
      int sg = s0 + st * 16 + s15;
      *(float2*)(p.out + (size_t)sg * 24 + n0)     = make_float2(acc[0], acc[1]);
      *(float2*)(p.out + (size_t)sg * 24 + n0 + 2) = make_float2(acc[2], acc[3]);
    }
  }
}

// ---------------- launch -----------------------------------------------------
extern "C" void kernel_launch(void* const* d_in, const int* in_sizes, int n_in,
                              void* d_out, int out_size, void* d_ws, size_t ws_size,
                              hipStream_t stream) {
  const float* xcont = (const float*)d_in[2];
  float* ws  = (float*)d_ws;
  char*  wsb = (char*)d_ws;
  ushort_t* w1p   = (ushort_t*)(wsb + 36864);    //  64 KB
  ushort_t* w2p   = (ushort_t*)(wsb + 102400);   // 256 KB
  ushort_t* wlp   = (ushort_t*)(wsb + 364544);   //  24 KB
  ushort_t* Apack = (ushort_t*)(wsb + 389120);   //  40 KB
  ushort_t* Bpack = (ushort_t*)(wsb + 430080);   //  12 KB

  PrepParams q;
  q.W1 = (const float*)d_in[20]; q.W2 = (const float*)d_in[22]; q.Wl = (const float*)d_in[24];
  q.w1p = w1p; q.w2p = w2p; q.wlp = wlp;
  q.Apack = Apack; q.Bpack = Bpack;
  q.xc = xcont; q.ws = ws;
  for (int i = 0; i < 12; ++i) q.wk[i] = (const float*)d_in[3 + i];
  prep_all<<<1048, 256, 0, stream>>>(q);
  bn_final<<<1, 256, 0, stream>>>(ws, ws, (const float*)d_in[18], (const float*)d_in[19]);

  FusedParams p;
  p.xw    = (const float*)d_in[0];
  p.xcat  = (const int*)d_in[1];
  p.xcont = xcont;
  p.E0 = (const float*)d_in[15]; p.E1 = (const float*)d_in[16]; p.E2 = (const float*)d_in[17];
  p.b1 = (const float*)d_in[21]; p.b2 = (const float*)d_in[23];
  p.Apack = Apack; p.Bpack = Bpack;
  p.w1p = w1p; p.w2p = w2p; p.wlp = wlp;
  p.stats = ws + 8192;
  p.out = (float*)d_out;
  fused_kernel<<<B_TOTAL / 64, 1024, 0, stream>>>(p);
}